// Round 5
// baseline (3606.618 us; speedup 1.0000x reference)
//
#include <hip/hip_runtime.h>
#include <cstdint>
#include <cstddef>

// DiscontinuedGRU: SEQ=2048, B=64, I=256, H=256.
// Pipeline:
//   K0a: X fp32 -> bf16 (ws)
//   K0b: Wih_f|Wih_b fp32 -> bf16 concat (ws)
//   K1 : GX[131072][1536] f16 = Xb @ Wcat^T + (bih + bhh_{r,z} folded; bhh_n NOT folded)
//   K2 : 128 WGs (one per (dir,batch) chain), Whh f16 register-resident,
//        v_dot2 matvec per step + gate math; h state in LDS (f16).
//   R3: kq-quad reduce via DPP quad_perm (VALU) instead of ds_swizzle (-117us, kept).
//   R4: GX/D loads hoisted to step top (raw regs, consumed after mid barrier) +
//       gh2 half-copy de-conflict (-725us, conflicts 5.03e7 -> 0, kept).
//   R5: (a) out store DEFERRED one step (pend reg, stored at next step top) — removes
//        the store-ack from the bottom barrier's vmcnt(0) drain; bottom drain is now
//        lgkm-only by construction, no asm barrier needed.
//       (b) full 8-way k-reduce in-wave: quad_perm x2 + row_half_mirror (lane^7) DPP —
//        same summation tree as the old two-half scheme (bitwise identical). Single gh
//        copy; thread j0 owns CONSECUTIVE rows 6*j0..6*j0+5; stride-12 layout makes the
//        8 rep-lane b128+b64 writes cover all 32 banks conflict-free. DS writes/step:
//        96 scalar -> 32 vector; gate reads 6 -> 3.
//   PERMANENT REVERTS (measured poison): lgkm-only asm barrier (+~1500us, R1/R2);
//        prefetch-across-bottom-barrier (requires said barrier).
// ws layout: Xb 67,108,864 B | Wcat 786,432 B | GX 402,653,184 B  (total ~449 MB)

#define SEQ 2048
#define BATCH 64

typedef __attribute__((ext_vector_type(8))) short short8;
typedef __attribute__((ext_vector_type(4))) float floatx4;
typedef __attribute__((ext_vector_type(2))) _Float16 h2;

#if defined(__has_builtin)
#if __has_builtin(__builtin_amdgcn_fdot2)
#define HAS_FDOT2 1
#endif
#if __has_builtin(__builtin_amdgcn_update_dpp)
#define HAS_DPP 1
#endif
#endif

__device__ inline float fdot2f(h2 a, h2 b, float c){
#ifdef HAS_FDOT2
  return __builtin_amdgcn_fdot2(a, b, c, false);
#else
  return c + (float)a.x * (float)b.x + (float)a.y * (float)b.y;
#endif
}

// Full sum over each 8-lane group (lane bits 0-2), all on the VALU pipe:
// quad_perm [1,0,3,2], quad_perm [2,3,0,1], then row_half_mirror (lane XOR 7, which
// after the quad reduce adds the other quad's sum). Tree: ((k0+k1)+(k2+k3)) +
// ((k4+k5)+(k6+k7)) — identical to the previous quad_add + cross-half f32 add.
__device__ inline float oct_add(float x){
#ifdef HAS_DPP
  int t1 = __builtin_amdgcn_update_dpp(0, __builtin_bit_cast(int, x), 0xB1, 0xF, 0xF, false);
  x += __builtin_bit_cast(float, t1);
  int t2 = __builtin_amdgcn_update_dpp(0, __builtin_bit_cast(int, x), 0x4E, 0xF, 0xF, false);
  x += __builtin_bit_cast(float, t2);
  int t3 = __builtin_amdgcn_update_dpp(0, __builtin_bit_cast(int, x), 0x141, 0xF, 0xF, false);
  x += __builtin_bit_cast(float, t3);
  return x;
#else
  x += __shfl_xor(x, 1);
  x += __shfl_xor(x, 2);
  x += __shfl_xor(x, 4);
  return x;
#endif
}

__device__ inline unsigned short f2bf(float f){
  union { float f; unsigned int u; } a; a.f = f;
  unsigned int u = a.u;
  unsigned int r = (u + 0x7fffu + ((u >> 16) & 1u)) >> 16;
  return (unsigned short)r;
}

__global__ __launch_bounds__(256) void cvt_x_kernel(const float* __restrict__ X,
                                                    unsigned short* __restrict__ Xb){
  size_t i = (size_t)blockIdx.x * 256 + threadIdx.x;   // one float4 per thread
  float4 v = ((const float4*)X)[i];
  ushort4 o;
  o.x = f2bf(v.x); o.y = f2bf(v.y); o.z = f2bf(v.z); o.w = f2bf(v.w);
  ((ushort4*)Xb)[i] = o;
}

__global__ __launch_bounds__(256) void cvt_w_kernel(const float* __restrict__ Wf,
                                                    const float* __restrict__ Wb,
                                                    unsigned short* __restrict__ Wcat){
  int i = blockIdx.x * 256 + threadIdx.x;              // 0..393215
  float v = (i < 768 * 256) ? Wf[i] : Wb[i - 768 * 256];
  Wcat[i] = f2bf(v);
}

// ---------------- GX GEMM: M=131072, N=1536, K=256, bf16 MFMA ----------------
// Block: 256 thr (4 waves). Tile BM=64, BN=128, BK=64. Wave w: rows [16w,16w+16) x 128 cols.
__global__ __launch_bounds__(256) void gx_gemm_kernel(
    const unsigned short* __restrict__ Xb,    // [131072][256] bf16
    const unsigned short* __restrict__ Wcat,  // [1536][256]  bf16 (row n, k-contig = B^T)
    const float* __restrict__ bih_f, const float* __restrict__ bhh_f,
    const float* __restrict__ bih_b, const float* __restrict__ bhh_b,
    _Float16* __restrict__ GX)                // [131072][1536] f16
{
  __shared__ unsigned short Al[64][72];   // +8 pad: stride 36 words
  __shared__ unsigned short Bl[128][72];
  const int tid  = threadIdx.x;
  const int lane = tid & 63;
  const int w    = tid >> 6;
  const size_t m0 = (size_t)blockIdx.x * 64;
  const int    n0 = blockIdx.y * 128;

  floatx4 acc[8];
  #pragma unroll
  for (int i = 0; i < 8; i++) acc[i] = (floatx4)0.f;

  const int ar = tid >> 2, ak = (tid & 3) * 16;   // A stage: 16 halves/thread
  const int bn = tid >> 1, bk = (tid & 1) * 32;   // B stage: 32 halves/thread

  for (int kc = 0; kc < 4; kc++){
    const int kb = kc * 64;
    { const uint4* s = (const uint4*)(Xb + (m0 + ar) * 256 + kb + ak);
      uint4 u0 = s[0], u1 = s[1];
      *(uint4*)&Al[ar][ak]     = u0;
      *(uint4*)&Al[ar][ak + 8] = u1;
    }
    { const uint4* s = (const uint4*)(Wcat + (size_t)(n0 + bn) * 256 + kb + bk);
      uint4 u0 = s[0], u1 = s[1], u2 = s[2], u3 = s[3];
      *(uint4*)&Bl[bn][bk]      = u0;
      *(uint4*)&Bl[bn][bk + 8]  = u1;
      *(uint4*)&Bl[bn][bk + 16] = u2;
      *(uint4*)&Bl[bn][bk + 24] = u3;
    }
    __syncthreads();
    #pragma unroll
    for (int ks = 0; ks < 2; ks++){
      const int kl = ks * 32 + (lane >> 4) * 8;
      short8 af = *(const short8*)&Al[w * 16 + (lane & 15)][kl];
      #pragma unroll
      for (int nt = 0; nt < 8; nt++){
        short8 bf = *(const short8*)&Bl[nt * 16 + (lane & 15)][kl];
        acc[nt] = __builtin_amdgcn_mfma_f32_16x16x32_bf16(af, bf, acc[nt], 0, 0, 0);
      }
    }
    __syncthreads();
  }
  // epilogue: D col = lane&15, row = (lane>>4)*4 + reg  [verified m89/m91]
  #pragma unroll
  for (int nt = 0; nt < 8; nt++){
    const int n_g = n0 + nt * 16 + (lane & 15);
    const int nl  = (n_g < 768) ? n_g : n_g - 768;
    const float* bih = (n_g < 768) ? bih_f : bih_b;
    const float* bhh = (n_g < 768) ? bhh_f : bhh_b;
    // fold bih (all gates) + bhh for r,z only; bhh_n applied inside scan (r * (hn + bhh_n))
    const float bias = bih[nl] + ((nl < 512) ? bhh[nl] : 0.f);
    #pragma unroll
    for (int r = 0; r < 4; r++){
      const size_t m_g = m0 + w * 16 + (lane >> 4) * 4 + r;
      GX[m_g * 1536 + n_g] = (_Float16)(acc[nt][r] + bias);
    }
  }
}

// ---------------- Recurrent scan: 128 WGs x 1024 thr, 1 chain each ----------------
// thread t: j0 = t>>3 (0..127), kq = t&7 (k-slice of 32). Owns rows 6*j0 .. 6*j0+5.
// Whh f16 in ~96 regs/thread. h state: LDS f16, slice-padded (stride 40 halves) so the
// 8 distinct per-wave b128 addresses land on 8 distinct bank quads (conflict-free).
// gh layout: row r at ghl[12*(r/6) + r%6] — stride 12 makes the 8 rep-lane b128/b64
// writes per wave cover all 32 banks exactly once (12*j0 mod 32 all-distinct for
// j0 in an 8-group).
__global__ __launch_bounds__(1024) void gru_scan_kernel(
    const float* __restrict__ Whh_f, const float* __restrict__ Whh_b,
    const float* __restrict__ bhh_f, const float* __restrict__ bhh_b,
    const int* __restrict__ D,
    const _Float16* __restrict__ GX,
    float* __restrict__ out)
{
  const int wg  = blockIdx.x;       // 0..127
  const int dir = wg & 1;
  const int b   = wg >> 1;
  const float* Whh = dir ? Whh_b : Whh_f;
  const float* bhh = dir ? bhh_b : bhh_f;
  const int tid   = threadIdx.x;
  const int j0    = tid >> 3;
  const int kq    = tid & 7;
  const int kbase = kq * 32;

  __shared__ _Float16 hbuf[8 * 40];    // slice q at q*40 (32 valid + 8 pad)
  __shared__ float    ghl[128 * 12];   // row r at 12*(r/6)+r%6 (6 used + 6 pad)

  // persistent weights: rows 6*j0 + q, k in [kbase, kbase+32)
  h2 wreg[6][4][4];
  #pragma unroll
  for (int q = 0; q < 6; q++){
    const float* wr = Whh + (size_t)(6 * j0 + q) * 256 + kbase;
    #pragma unroll
    for (int c = 0; c < 4; c++){
      float4 f0 = *(const float4*)(wr + c * 8);
      float4 f1 = *(const float4*)(wr + c * 8 + 4);
      wreg[q][c][0] = h2{(_Float16)f0.x, (_Float16)f0.y};
      wreg[q][c][1] = h2{(_Float16)f0.z, (_Float16)f0.w};
      wreg[q][c][2] = h2{(_Float16)f1.x, (_Float16)f1.y};
      wreg[q][c][3] = h2{(_Float16)f1.z, (_Float16)f1.w};
    }
  }

  const bool gate = (tid < 256);      // waves 0-3, whole waves -> no divergence cost elsewhere
  float h_reg = 0.f;                  // fp32 h_in[j] for gate thread j = tid
  float bhhn  = 0.f;
  int a_r = 0, a_z = 0, a_n = 0;      // precomputed ghl word addresses (step-invariant)
  if (gate){
    bhhn = bhh[512 + tid];
    hbuf[((tid >> 5) * 40) + (tid & 31)] = (_Float16)0.f;
    a_r = (tid / 6) * 12 + (tid % 6);
    a_z = ((256 + tid) / 6) * 12 + ((256 + tid) % 6);
    a_n = ((512 + tid) / 6) * 12 + ((512 + tid) % 6);
  }
  __syncthreads();

  float  pend  = 0.f;                 // deferred out value (stored at next step top)
  size_t paddr = 0;

  for (int step = 0; step < SEQ; step++){
    const int t = dir ? (SEQ - 1 - step) : step;

    // Step top (gate waves): flush last step's deferred out store, then issue this
    // step's GX + D loads into RAW registers. All of these have the whole matvec
    // phase to complete before the mid barrier's vmcnt(0) drain.
    _Float16 pgr = (_Float16)0.f, pgz = (_Float16)0.f, pgn = (_Float16)0.f;
    int mraw = 0;
    if (gate){
      if (step > 0) out[paddr] = pend;
      const _Float16* gx = GX + ((size_t)t * BATCH + b) * 1536 + dir * 768;
      pgr = gx[tid];
      pgz = gx[256 + tid];
      pgn = gx[512 + tid];
      // fwd uses D[t+1] (clamped at last step, value dead); bwd uses D[t]
      const int tm = dir ? t : ((step < SEQ - 1) ? (t + 1) : t);
      mraw = D[(size_t)tm * BATCH + b];
    }

    float acc[6] = {0.f, 0.f, 0.f, 0.f, 0.f, 0.f};
    #pragma unroll
    for (int c = 0; c < 4; c++){
      uint4 u = *(const uint4*)&hbuf[kq * 40 + c * 8];
      h2 p0 = __builtin_bit_cast(h2, u.x);
      h2 p1 = __builtin_bit_cast(h2, u.y);
      h2 p2 = __builtin_bit_cast(h2, u.z);
      h2 p3 = __builtin_bit_cast(h2, u.w);
      #pragma unroll
      for (int q = 0; q < 6; q++){
        acc[q] = fdot2f(wreg[q][c][0], p0, acc[q]);
        acc[q] = fdot2f(wreg[q][c][1], p1, acc[q]);
        acc[q] = fdot2f(wreg[q][c][2], p2, acc[q]);
        acc[q] = fdot2f(wreg[q][c][3], p3, acc[q]);
      }
    }
    // full 8-way k-reduce on the VALU pipe; every lane then holds the row sums
    #pragma unroll
    for (int q = 0; q < 6; q++) acc[q] = oct_add(acc[q]);
    if ((tid & 7) == 0){               // one rep lane per j0: 2 vector writes
      float4 v0; v0.x = acc[0]; v0.y = acc[1]; v0.z = acc[2]; v0.w = acc[3];
      float2 v1; v1.x = acc[4]; v1.y = acc[5];
      *(float4*)&ghl[12 * j0]     = v0;
      *(float2*)&ghl[12 * j0 + 4] = v1;
    }
    __syncthreads();

    if (gate){
      const int j = tid;
      // consume the loads issued before the matvec (resident by now)
      const float gxr = (float)pgr;
      const float gxz = (float)pgz;
      const float gxn = (float)pgn;
      float mnext = (float)mraw;
      if (dir == 0 && step == SEQ - 1) mnext = 0.f;   // clamped tail value is dead
      const float ghr = ghl[a_r];
      const float ghz = ghl[a_z];
      const float ghn = ghl[a_n];
      const float r = 1.f / (1.f + __expf(-(gxr + ghr)));
      const float z = 1.f / (1.f + __expf(-(gxz + ghz)));
      const float e = __expf(2.f * (gxn + r * (ghn + bhhn)));
      const float n = 1.f - 2.f / (e + 1.f);
      const float hnew = (1.f - z) * n + z * h_reg;
      const size_t row = (size_t)t * BATCH + b;
      pend  = hnew;                    // store deferred to next step top (no vmem
      paddr = row * 512 + dir * 256 + j; // issued between here and bottom barrier)
      h_reg = (1.f - mnext) * hnew;
      hbuf[((j >> 5) * 40) + (j & 31)] = (_Float16)h_reg;
    }
    __syncthreads();
  }
  if (gate) out[paddr] = pend;         // final deferred store
}

extern "C" void kernel_launch(void* const* d_in, const int* in_sizes, int n_in,
                              void* d_out, int out_size, void* d_ws, size_t ws_size,
                              hipStream_t stream)
{
  const float* X     = (const float*)d_in[0];
  const int*   D     = (const int*)  d_in[1];
  const float* Wih_f = (const float*)d_in[2];
  const float* Whh_f = (const float*)d_in[3];
  const float* bih_f = (const float*)d_in[4];
  const float* bhh_f = (const float*)d_in[5];
  const float* Wih_b = (const float*)d_in[6];
  const float* Whh_b = (const float*)d_in[7];
  const float* bih_b = (const float*)d_in[8];
  const float* bhh_b = (const float*)d_in[9];
  float* out = (float*)d_out;

  char* ws = (char*)d_ws;
  unsigned short* Xb   = (unsigned short*)ws;               // 67,108,864 B
  unsigned short* Wcat = (unsigned short*)(ws + 67108864);  //    786,432 B
  _Float16*       GX   = (_Float16*)(ws + 67895296);        // 402,653,184 B

  cvt_x_kernel<<<dim3(32768), 256, 0, stream>>>(X, Xb);
  cvt_w_kernel<<<dim3(1536), 256, 0, stream>>>(Wih_f, Wih_b, Wcat);
  gx_gemm_kernel<<<dim3(2048, 12), 256, 0, stream>>>(Xb, Wcat, bih_f, bhh_f, bih_b, bhh_b, GX);
  gru_scan_kernel<<<dim3(128), 1024, 0, stream>>>(Whh_f, Whh_b, bhh_f, bhh_b, D, GX, out);
}

// Round 6
// 3393.019 us; speedup vs baseline: 1.0630x; 1.0630x over previous
//
#include <hip/hip_runtime.h>
#include <cstdint>
#include <cstddef>

// DiscontinuedGRU: SEQ=2048, B=64, I=256, H=256.
// Pipeline:
//   K0a: X fp32 -> bf16 (ws)
//   K0b: Wih_f|Wih_b fp32 -> bf16 concat (ws)
//   K1 : GX[131072][1536] f16 = Xb @ Wcat^T + (bih + bhh_{r,z} folded; bhh_n NOT folded)
//   K2 : 128 WGs (one per (dir,batch) chain), 1024 thr.
//   R6 STRUCTURAL REWRITE of the scan ("fused single-phase"):
//     thread (j = tid>>2, kq = tid&3) owns rows {j, 256+j, 512+j} x k-slice
//     [64kq, 64kq+64). After a quad DPP reduce (quad == the 4 kq slices of one j),
//     EVERY lane holds all 3 gate sums for its j -> gate computed inline,
//     redundantly x4 (free: VALU-parallel, no divergence). This deletes the
//     gh LDS exchange, the mid barrier, and the 4-wave serial gate phase
//     (prev structure idled 12/16 waves through it). ONE barrier/step with
//     double-buffered h (write buf[s^1], read buf[s]).
//     h slices padded to 72 halves: the 4 distinct 16-lane-broadcast b128 read
//     addresses land on disjoint bank quads (kq*36%32 = 4kq).
//   History: R3 DPP quad reduce (-117us); R4 GX-hoist + gh de-pad (-725us, kept ideas);
//     R5 deferred-store + single-copy-reduce REGRESSED (+445us, both discarded).
//   PERMANENT REVERTS (measured poison): lgkm-only asm barrier (R1/R2, +~1500us);
//     prefetch-across-barrier; deferred out store (R5 suspect).
// ws layout: Xb 67,108,864 B | Wcat 786,432 B | GX 402,653,184 B  (total ~449 MB)

#define SEQ 2048
#define BATCH 64

typedef __attribute__((ext_vector_type(8))) short short8;
typedef __attribute__((ext_vector_type(4))) float floatx4;
typedef __attribute__((ext_vector_type(2))) _Float16 h2;

#if defined(__has_builtin)
#if __has_builtin(__builtin_amdgcn_fdot2)
#define HAS_FDOT2 1
#endif
#if __has_builtin(__builtin_amdgcn_update_dpp)
#define HAS_DPP 1
#endif
#endif

__device__ inline float fdot2f(h2 a, h2 b, float c){
#ifdef HAS_FDOT2
  return __builtin_amdgcn_fdot2(a, b, c, false);
#else
  return c + (float)a.x * (float)b.x + (float)a.y * (float)b.y;
#endif
}

// sum over the 4 lanes of each quad (lane bits 0,1) — VALU DPP, no DS-pipe traffic.
// Call-site is fully convergent. Proven in R3 (-117us vs ds_swizzle).
__device__ inline float quad_add(float x){
#ifdef HAS_DPP
  int t1 = __builtin_amdgcn_update_dpp(0, __builtin_bit_cast(int, x), 0xB1, 0xF, 0xF, false); // quad_perm [1,0,3,2]
  x += __builtin_bit_cast(float, t1);
  int t2 = __builtin_amdgcn_update_dpp(0, __builtin_bit_cast(int, x), 0x4E, 0xF, 0xF, false); // quad_perm [2,3,0,1]
  x += __builtin_bit_cast(float, t2);
  return x;
#else
  x += __shfl_xor(x, 1);
  x += __shfl_xor(x, 2);
  return x;
#endif
}

__device__ inline unsigned short f2bf(float f){
  union { float f; unsigned int u; } a; a.f = f;
  unsigned int u = a.u;
  unsigned int r = (u + 0x7fffu + ((u >> 16) & 1u)) >> 16;
  return (unsigned short)r;
}

__global__ __launch_bounds__(256) void cvt_x_kernel(const float* __restrict__ X,
                                                    unsigned short* __restrict__ Xb){
  size_t i = (size_t)blockIdx.x * 256 + threadIdx.x;   // one float4 per thread
  float4 v = ((const float4*)X)[i];
  ushort4 o;
  o.x = f2bf(v.x); o.y = f2bf(v.y); o.z = f2bf(v.z); o.w = f2bf(v.w);
  ((ushort4*)Xb)[i] = o;
}

__global__ __launch_bounds__(256) void cvt_w_kernel(const float* __restrict__ Wf,
                                                    const float* __restrict__ Wb,
                                                    unsigned short* __restrict__ Wcat){
  int i = blockIdx.x * 256 + threadIdx.x;              // 0..393215
  float v = (i < 768 * 256) ? Wf[i] : Wb[i - 768 * 256];
  Wcat[i] = f2bf(v);
}

// ---------------- GX GEMM: M=131072, N=1536, K=256, bf16 MFMA ----------------
// Block: 256 thr (4 waves). Tile BM=64, BN=128, BK=64. Wave w: rows [16w,16w+16) x 128 cols.
__global__ __launch_bounds__(256) void gx_gemm_kernel(
    const unsigned short* __restrict__ Xb,    // [131072][256] bf16
    const unsigned short* __restrict__ Wcat,  // [1536][256]  bf16 (row n, k-contig = B^T)
    const float* __restrict__ bih_f, const float* __restrict__ bhh_f,
    const float* __restrict__ bih_b, const float* __restrict__ bhh_b,
    _Float16* __restrict__ GX)                // [131072][1536] f16
{
  __shared__ unsigned short Al[64][72];   // +8 pad: stride 36 words
  __shared__ unsigned short Bl[128][72];
  const int tid  = threadIdx.x;
  const int lane = tid & 63;
  const int w    = tid >> 6;
  const size_t m0 = (size_t)blockIdx.x * 64;
  const int    n0 = blockIdx.y * 128;

  floatx4 acc[8];
  #pragma unroll
  for (int i = 0; i < 8; i++) acc[i] = (floatx4)0.f;

  const int ar = tid >> 2, ak = (tid & 3) * 16;   // A stage: 16 halves/thread
  const int bn = tid >> 1, bk = (tid & 1) * 32;   // B stage: 32 halves/thread

  for (int kc = 0; kc < 4; kc++){
    const int kb = kc * 64;
    { const uint4* s = (const uint4*)(Xb + (m0 + ar) * 256 + kb + ak);
      uint4 u0 = s[0], u1 = s[1];
      *(uint4*)&Al[ar][ak]     = u0;
      *(uint4*)&Al[ar][ak + 8] = u1;
    }
    { const uint4* s = (const uint4*)(Wcat + (size_t)(n0 + bn) * 256 + kb + bk);
      uint4 u0 = s[0], u1 = s[1], u2 = s[2], u3 = s[3];
      *(uint4*)&Bl[bn][bk]      = u0;
      *(uint4*)&Bl[bn][bk + 8]  = u1;
      *(uint4*)&Bl[bn][bk + 16] = u2;
      *(uint4*)&Bl[bn][bk + 24] = u3;
    }
    __syncthreads();
    #pragma unroll
    for (int ks = 0; ks < 2; ks++){
      const int kl = ks * 32 + (lane >> 4) * 8;
      short8 af = *(const short8*)&Al[w * 16 + (lane & 15)][kl];
      #pragma unroll
      for (int nt = 0; nt < 8; nt++){
        short8 bf = *(const short8*)&Bl[nt * 16 + (lane & 15)][kl];
        acc[nt] = __builtin_amdgcn_mfma_f32_16x16x32_bf16(af, bf, acc[nt], 0, 0, 0);
      }
    }
    __syncthreads();
  }
  // epilogue: D col = lane&15, row = (lane>>4)*4 + reg  [verified m89/m91]
  #pragma unroll
  for (int nt = 0; nt < 8; nt++){
    const int n_g = n0 + nt * 16 + (lane & 15);
    const int nl  = (n_g < 768) ? n_g : n_g - 768;
    const float* bih = (n_g < 768) ? bih_f : bih_b;
    const float* bhh = (n_g < 768) ? bhh_f : bhh_b;
    // fold bih (all gates) + bhh for r,z only; bhh_n applied inside scan (r * (hn + bhh_n))
    const float bias = bih[nl] + ((nl < 512) ? bhh[nl] : 0.f);
    #pragma unroll
    for (int r = 0; r < 4; r++){
      const size_t m_g = m0 + w * 16 + (lane >> 4) * 4 + r;
      GX[m_g * 1536 + n_g] = (_Float16)(acc[nt][r] + bias);
    }
  }
}

// ---------------- Recurrent scan: 128 WGs x 1024 thr, 1 chain each ----------------
// Fused single-phase structure (see header). Thread: j = tid>>2 (0..255), kq = tid&3.
// Owns rows {j, 256+j, 512+j}, k in [64kq, 64kq+64). Weights: 96 h2 regs/thread.
// h state: double-buffered LDS f16, slice kq at kq*72 (64 valid + 8 pad halves):
// the 4 distinct broadcast read addresses hit bank quads {4kq+4c} — disjoint.
__global__ __launch_bounds__(1024) void gru_scan_kernel(
    const float* __restrict__ Whh_f, const float* __restrict__ Whh_b,
    const float* __restrict__ bhh_f, const float* __restrict__ bhh_b,
    const int* __restrict__ D,
    const _Float16* __restrict__ GX,
    float* __restrict__ out)
{
  const int wg  = blockIdx.x;       // 0..127
  const int dir = wg & 1;
  const int b   = wg >> 1;
  const float* Whh = dir ? Whh_b : Whh_f;
  const float* bhh = dir ? bhh_b : bhh_f;
  const int tid = threadIdx.x;
  const int j   = tid >> 2;         // 0..255 — the h/gate index this thread owns
  const int kq  = tid & 3;          // k-slice of 64

  __shared__ _Float16 hb[2][4 * 72];   // double-buffered h; slice kq at kq*72

  // persistent weights: rows j (r), 256+j (z), 512+j (n); k in [64kq, 64kq+64)
  h2 wreg[3][8][4];
  #pragma unroll
  for (int g = 0; g < 3; g++){
    const float* wr = Whh + (size_t)(g * 256 + j) * 256 + kq * 64;
    #pragma unroll
    for (int c = 0; c < 8; c++){
      float4 f0 = *(const float4*)(wr + c * 8);
      float4 f1 = *(const float4*)(wr + c * 8 + 4);
      wreg[g][c][0] = h2{(_Float16)f0.x, (_Float16)f0.y};
      wreg[g][c][1] = h2{(_Float16)f0.z, (_Float16)f0.w};
      wreg[g][c][2] = h2{(_Float16)f1.x, (_Float16)f1.y};
      wreg[g][c][3] = h2{(_Float16)f1.z, (_Float16)f1.w};
    }
  }

  const float bhhn = bhh[512 + j];
  float h_reg = 0.f;                // h_in[j], tracked redundantly by all 4 kq lanes
  if (tid < 288) hb[0][tid] = (_Float16)0.f;
  __syncthreads();

  const int hw_addr = ((j >> 6) * 72) + (j & 63);   // where h[j] lives in a buffer

  for (int step = 0; step < SEQ; step++){
    const int t   = dir ? (SEQ - 1 - step) : step;
    const int cur = step & 1;

    // Issue this step's GX + D loads into RAW regs; consumed ~after the matvec via a
    // per-wave counted waitcnt (no barrier between issue and use — R4's proven pattern,
    // now without barrier amplification).
    const _Float16* gx = GX + ((size_t)t * BATCH + b) * 1536 + dir * 768;
    _Float16 pgr = gx[j];
    _Float16 pgz = gx[256 + j];
    _Float16 pgn = gx[512 + j];
    const int tm = dir ? t : ((step < SEQ - 1) ? (t + 1) : t);
    const int mraw = D[(size_t)tm * BATCH + b];

    // matvec: 3 gate rows x 64 k-slice
    const _Float16* hcur = &hb[cur][kq * 72];
    float ar = 0.f, az = 0.f, an = 0.f;
    #pragma unroll
    for (int c = 0; c < 8; c++){
      uint4 u = *(const uint4*)&hcur[c * 8];
      h2 p0 = __builtin_bit_cast(h2, u.x);
      h2 p1 = __builtin_bit_cast(h2, u.y);
      h2 p2 = __builtin_bit_cast(h2, u.z);
      h2 p3 = __builtin_bit_cast(h2, u.w);
      ar = fdot2f(wreg[0][c][0], p0, ar); ar = fdot2f(wreg[0][c][1], p1, ar);
      ar = fdot2f(wreg[0][c][2], p2, ar); ar = fdot2f(wreg[0][c][3], p3, ar);
      az = fdot2f(wreg[1][c][0], p0, az); az = fdot2f(wreg[1][c][1], p1, az);
      az = fdot2f(wreg[1][c][2], p2, az); az = fdot2f(wreg[1][c][3], p3, az);
      an = fdot2f(wreg[2][c][0], p0, an); an = fdot2f(wreg[2][c][1], p1, an);
      an = fdot2f(wreg[2][c][2], p2, an); an = fdot2f(wreg[2][c][3], p3, an);
    }
    // quad = the 4 kq slices of this j -> full k-sums in every lane
    ar = quad_add(ar); az = quad_add(az); an = quad_add(an);

    // gate math, computed redundantly by all 4 lanes of the quad (identical inputs)
    const float gxr = (float)pgr;
    const float gxz = (float)pgz;
    const float gxn = (float)pgn;
    const float r = 1.f / (1.f + __expf(-(gxr + ar)));
    const float z = 1.f / (1.f + __expf(-(gxz + az)));
    const float e = __expf(2.f * (gxn + r * (an + bhhn)));
    const float n = 1.f - 2.f / (e + 1.f);
    const float hnew = (1.f - z) * n + z * h_reg;

    float mnext = (float)mraw;
    if (dir == 0 && step == SEQ - 1) mnext = 0.f;   // clamped tail value is dead
    h_reg = (1.f - mnext) * hnew;

    if (kq == 0){
      out[((size_t)t * BATCH + b) * 512 + dir * 256 + j] = hnew;
      hb[cur ^ 1][hw_addr] = (_Float16)h_reg;
    }
    __syncthreads();
  }
}

extern "C" void kernel_launch(void* const* d_in, const int* in_sizes, int n_in,
                              void* d_out, int out_size, void* d_ws, size_t ws_size,
                              hipStream_t stream)
{
  const float* X     = (const float*)d_in[0];
  const int*   D     = (const int*)  d_in[1];
  const float* Wih_f = (const float*)d_in[2];
  const float* Whh_f = (const float*)d_in[3];
  const float* bih_f = (const float*)d_in[4];
  const float* bhh_f = (const float*)d_in[5];
  const float* Wih_b = (const float*)d_in[6];
  const float* Whh_b = (const float*)d_in[7];
  const float* bih_b = (const float*)d_in[8];
  const float* bhh_b = (const float*)d_in[9];
  float* out = (float*)d_out;

  char* ws = (char*)d_ws;
  unsigned short* Xb   = (unsigned short*)ws;               // 67,108,864 B
  unsigned short* Wcat = (unsigned short*)(ws + 67108864);  //    786,432 B
  _Float16*       GX   = (_Float16*)(ws + 67895296);        // 402,653,184 B

  cvt_x_kernel<<<dim3(32768), 256, 0, stream>>>(X, Xb);
  cvt_w_kernel<<<dim3(1536), 256, 0, stream>>>(Wih_f, Wih_b, Wcat);
  gx_gemm_kernel<<<dim3(2048, 12), 256, 0, stream>>>(Xb, Wcat, bih_f, bhh_f, bih_b, bhh_b, GX);
  gru_scan_kernel<<<dim3(128), 1024, 0, stream>>>(Whh_f, Whh_b, bhh_f, bhh_b, D, GX, out);
}